// Round 1
// baseline (582.157 us; speedup 1.0000x reference)
//
#include <hip/hip_runtime.h>
#include <hip/hip_bf16.h>

// SparseGAT forward, fp32 end-to-end.
// Sizes: N=50000 nodes, FI=256, FO=64, H=8, E=800000 edges.
// ws layout (floats): T[N*512] | aw[N*8] | den[N*8] | acc[N*64]

#define FI 256
#define FO 64
#define NH 8
#define FC (NH * FO)  // 512 combined feature columns

// ---------------- K1: T = x @ W  (all heads), fp32 tiled GEMM ---------------
// grid: (ceil(N/64), 8 heads), block: 256 threads, 4x4 micro-tile each.
__global__ __launch_bounds__(256)
void k1_gemm(const float* __restrict__ x, const float* __restrict__ W,
             float* __restrict__ T, int N) {
  __shared__ float As[64][65];   // +1 pad: conflict-free column reads
  __shared__ float Bs[64][64];   // reads are broadcast across ty -> no pad
  const int h  = blockIdx.y;
  const int bm = blockIdx.x * 64;
  const int t  = threadIdx.x;
  const int tx = t & 15, ty = t >> 4;
  const float* Wh = W + (size_t)h * (FI * FO);

  float acc[4][4] = {};

  for (int k0 = 0; k0 < FI; k0 += 64) {
    // cooperative load: 64x64 A tile and 64x64 B tile, float4 each
    #pragma unroll
    for (int r = 0; r < 4; ++r) {
      int i = t + r * 256;          // float4 index 0..1023
      int mm = (i * 4) >> 6;        // row within tile
      int kk = (i * 4) & 63;        // col within tile
      int row = bm + mm;
      float4 av = (row < N)
          ? *reinterpret_cast<const float4*>(&x[(size_t)row * FI + k0 + kk])
          : make_float4(0.f, 0.f, 0.f, 0.f);
      As[mm][kk + 0] = av.x; As[mm][kk + 1] = av.y;
      As[mm][kk + 2] = av.z; As[mm][kk + 3] = av.w;
      // B tile: Bs[k][f] = W[h][k0+k][f]
      float4 bv = *reinterpret_cast<const float4*>(&Wh[(size_t)(k0 + mm) * FO + kk]);
      *reinterpret_cast<float4*>(&Bs[mm][kk]) = bv;
    }
    __syncthreads();

    #pragma unroll
    for (int k = 0; k < 64; ++k) {
      float a0 = As[ty * 4 + 0][k];
      float a1 = As[ty * 4 + 1][k];
      float a2 = As[ty * 4 + 2][k];
      float a3 = As[ty * 4 + 3][k];
      float4 b4 = *reinterpret_cast<const float4*>(&Bs[k][tx * 4]);
      acc[0][0] = fmaf(a0, b4.x, acc[0][0]); acc[0][1] = fmaf(a0, b4.y, acc[0][1]);
      acc[0][2] = fmaf(a0, b4.z, acc[0][2]); acc[0][3] = fmaf(a0, b4.w, acc[0][3]);
      acc[1][0] = fmaf(a1, b4.x, acc[1][0]); acc[1][1] = fmaf(a1, b4.y, acc[1][1]);
      acc[1][2] = fmaf(a1, b4.z, acc[1][2]); acc[1][3] = fmaf(a1, b4.w, acc[1][3]);
      acc[2][0] = fmaf(a2, b4.x, acc[2][0]); acc[2][1] = fmaf(a2, b4.y, acc[2][1]);
      acc[2][2] = fmaf(a2, b4.z, acc[2][2]); acc[2][3] = fmaf(a2, b4.w, acc[2][3]);
      acc[3][0] = fmaf(a3, b4.x, acc[3][0]); acc[3][1] = fmaf(a3, b4.y, acc[3][1]);
      acc[3][2] = fmaf(a3, b4.z, acc[3][2]); acc[3][3] = fmaf(a3, b4.w, acc[3][3]);
    }
    __syncthreads();
  }

  #pragma unroll
  for (int i = 0; i < 4; ++i) {
    int row = bm + ty * 4 + i;
    if (row < N) {
      float4 v = make_float4(acc[i][0], acc[i][1], acc[i][2], acc[i][3]);
      *reinterpret_cast<float4*>(&T[(size_t)row * FC + h * FO + tx * 4]) = v;
    }
  }
}

// ---------------- K2: aw[n,h] = dot(T[n, h*64 : h*64+64], a[h]) -------------
// grid: N blocks of 512 threads; wave w handles head w.
__global__ __launch_bounds__(512)
void k2_aw(const float* __restrict__ T, const float* __restrict__ a,
           float* __restrict__ aw, int N) {
  int n = blockIdx.x;
  int w = threadIdx.x >> 6;
  int lane = threadIdx.x & 63;
  float v = T[(size_t)n * FC + w * FO + lane] * a[w * FO + lane];
  #pragma unroll
  for (int off = 32; off; off >>= 1) v += __shfl_down(v, off);
  if (lane == 0) aw[n * NH + w] = v;
}

// ---------------- K3: den[r,h] += exp(leaky_relu(aw_r + aw_c)) --------------
__global__ __launch_bounds__(256)
void k3_den(const int* __restrict__ rows, const int* __restrict__ cols,
            const float* __restrict__ aw, float* __restrict__ den, int E) {
  int idx = blockIdx.x * blockDim.x + threadIdx.x;
  if (idx >= E * NH) return;
  int e = idx >> 3, h = idx & 7;
  int r = rows[e], c = cols[e];
  float s = aw[r * NH + h] + aw[c * NH + h];
  float lr = s > 0.f ? s : 0.2f * s;
  atomicAdd(&den[r * NH + h], __expf(lr));
}

// ---------------- K4: acc[r,f] += sum_h coef_h * T[c, h*64+f] ---------------
// one wave per edge; single atomicAdd per lane.
__global__ __launch_bounds__(256)
void k4_agg(const int* __restrict__ rows, const int* __restrict__ cols,
            const float* __restrict__ aw, const float* __restrict__ den,
            const float* __restrict__ T, float* __restrict__ acc, int E) {
  int wid = (int)((blockIdx.x * (size_t)blockDim.x + threadIdx.x) >> 6);
  int lane = threadIdx.x & 63;
  if (wid >= E) return;
  int r = rows[wid], c = cols[wid];
  const float* tr = T + (size_t)c * FC;
  float sum = 0.f;
  #pragma unroll
  for (int h = 0; h < NH; ++h) {
    float s = aw[r * NH + h] + aw[c * NH + h];
    float lr = s > 0.f ? s : 0.2f * s;
    float coef = __expf(lr) / den[r * NH + h];
    sum = fmaf(coef, tr[h * FO + lane], sum);
  }
  atomicAdd(&acc[(size_t)r * FO + lane], sum);
}

// ---------------- K5: out = relu((acc + sum_h b[h]) / 8) --------------------
__global__ __launch_bounds__(256)
void k5_final(const float* __restrict__ acc, const float* __restrict__ b,
              float* __restrict__ out, int N) {
  int idx = blockIdx.x * blockDim.x + threadIdx.x;
  if (idx >= N * FO) return;
  int f = idx & (FO - 1);
  float sb = 0.f;
  #pragma unroll
  for (int h = 0; h < NH; ++h) sb += b[h * FO + f];
  float v = (acc[idx] + sb) * 0.125f;
  out[idx] = v > 0.f ? v : 0.f;
}

extern "C" void kernel_launch(void* const* d_in, const int* in_sizes, int n_in,
                              void* d_out, int out_size, void* d_ws, size_t ws_size,
                              hipStream_t stream) {
  const float* x    = (const float*)d_in[0];
  const float* W    = (const float*)d_in[1];
  const float* a    = (const float*)d_in[2];
  const float* b    = (const float*)d_in[3];
  const int*   rows = (const int*)d_in[4];
  const int*   cols = (const int*)d_in[5];
  const int N = in_sizes[0] / FI;
  const int E = in_sizes[4];

  float* T   = (float*)d_ws;
  float* aw  = T   + (size_t)N * FC;
  float* den = aw  + (size_t)N * NH;
  float* acc = den + (size_t)N * NH;
  float* out = (float*)d_out;

  // zero accumulators (harness does not re-poison between replays)
  hipMemsetAsync(den, 0, (size_t)N * NH * sizeof(float), stream);
  hipMemsetAsync(acc, 0, (size_t)N * FO * sizeof(float), stream);

  k1_gemm<<<dim3((N + 63) / 64, NH), 256, 0, stream>>>(x, W, T, N);
  k2_aw<<<N, 512, 0, stream>>>(T, a, aw, N);
  k3_den<<<(E * NH + 255) / 256, 256, 0, stream>>>(rows, cols, aw, den, E);
  k4_agg<<<(E + 3) / 4, 256, 0, stream>>>(rows, cols, aw, den, T, acc, E);
  k5_final<<<(N * FO + 255) / 256, 256, 0, stream>>>(acc, b, out, N);
}

// Round 2
// 397.261 us; speedup vs baseline: 1.4654x; 1.4654x over previous
//
#include <hip/hip_runtime.h>
#include <hip/hip_bf16.h>

// SparseGAT forward. fp16-MFMA feature transform, fp32 everywhere else.
// N=50000, FI=256, FO=64, H=8, E=800000.
//
// ws layout (bytes, 16B-aligned chunks):
//   Th  [N*512] fp16   51.2MB   (T, all heads, fp16)
//   xh  [N*256] fp16   25.6MB   (x in fp16; ALIASED by acc[N*64] f32 after K1)
//   Wth [8*64*256] fp16 0.26MB  (W transposed [h][f][k], fp16)
//   aw  [N*8]   f32     1.6MB
//   den [N*8]   f32     1.6MB
//   exc [E*8]   f32    25.6MB   (ex, divided in-place -> coef)

#define FI 256
#define FO 64
#define NH 8
#define FC (NH * FO)  // 512

typedef _Float16 f16x8 __attribute__((ext_vector_type(8)));
typedef float f32x16 __attribute__((ext_vector_type(16)));

// ---------------- P0: x fp32 -> fp16 ----------------------------------------
__global__ __launch_bounds__(256)
void p0_xconv(const float* __restrict__ x, _Float16* __restrict__ xh, int total4) {
  int i = blockIdx.x * 256 + threadIdx.x;
  if (i >= total4) return;
  float4 v = reinterpret_cast<const float4*>(x)[i];
  _Float16 o[4] = {(_Float16)v.x, (_Float16)v.y, (_Float16)v.z, (_Float16)v.w};
  *reinterpret_cast<uint2*>(&xh[(size_t)i * 4]) = *reinterpret_cast<uint2*>(o);
}

// ---------------- P1: W[h][k][f] -> Wth[h][f][k] fp16 -----------------------
__global__ __launch_bounds__(256)
void p1_wconv(const float* __restrict__ W, _Float16* __restrict__ Wth) {
  int idx = blockIdx.x * 256 + threadIdx.x;   // h*64*256 + f*256 + k
  if (idx >= NH * FO * FI) return;
  int k = idx & (FI - 1);
  int f = (idx >> 8) & (FO - 1);
  int h = idx >> 14;
  Wth[idx] = (_Float16)W[((size_t)h * FI + k) * FO + f];
}

// ---------------- K1: T = x @ W per head, fp16 MFMA -------------------------
// grid (ceil(N/64), 8), 256 threads = 4 waves (2x2 of 32x32 tiles).
__global__ __launch_bounds__(256)
void k1_mfma(const _Float16* __restrict__ xh, const _Float16* __restrict__ Wth,
             _Float16* __restrict__ Th, int N) {
  __shared__ _Float16 Xs[64][264];   // +8 pad: b128 reads at min 4-way conflict
  const int h   = blockIdx.y;
  const int bm  = blockIdx.x * 64;
  const int t   = threadIdx.x;
  const int lane = t & 63;
  const int wid  = t >> 6;
  const int wr = wid >> 1, wc = wid & 1;

  // stage 64x256 fp16 x-tile, 16B per thread per iter
  #pragma unroll
  for (int r = 0; r < 8; ++r) {
    int i = t + r * 256;          // chunk 0..2047 (8 halfs each)
    int row = i >> 5;
    int c8 = (i & 31) * 8;
    int grow = bm + row;
    f16x8 v = {};
    if (grow < N)
      v = *reinterpret_cast<const f16x8*>(&xh[(size_t)grow * FI + c8]);
    *reinterpret_cast<f16x8*>(&Xs[row][c8]) = v;
  }
  __syncthreads();

  const int l31 = lane & 31;
  const int kh  = (lane >> 5) * 8;
  const _Float16* Wcol = Wth + ((size_t)h * FO + wc * 32 + l31) * FI;
  const int arow = wr * 32 + l31;

  f32x16 acc = (f32x16)0.0f;
  #pragma unroll
  for (int kk = 0; kk < 16; ++kk) {
    f16x8 af = *reinterpret_cast<const f16x8*>(&Xs[arow][kk * 16 + kh]);
    f16x8 bf = *reinterpret_cast<const f16x8*>(&Wcol[kk * 16 + kh]);
    acc = __builtin_amdgcn_mfma_f32_32x32x16_f16(af, bf, acc, 0, 0, 0);
  }

  // C/D: col = lane&31, row = (reg&3) + 8*(reg>>2) + 4*(lane>>5)
  const int cbase = h * FO + wc * 32 + l31;
  #pragma unroll
  for (int reg = 0; reg < 16; ++reg) {
    int rr = (reg & 3) + 8 * (reg >> 2) + 4 * (lane >> 5);
    int grow = bm + wr * 32 + rr;
    if (grow < N) Th[(size_t)grow * FC + cbase] = (_Float16)acc[reg];
  }
}

// ---------------- K2: aw[n,h] = dot(T[n,h*64:], a[h]) -----------------------
__global__ __launch_bounds__(512)
void k2_aw(const _Float16* __restrict__ Th, const float* __restrict__ a,
           float* __restrict__ aw, int N) {
  int n = blockIdx.x;
  int w = threadIdx.x >> 6;
  int lane = threadIdx.x & 63;
  float v = (float)Th[(size_t)n * FC + w * FO + lane] * a[w * FO + lane];
  #pragma unroll
  for (int off = 32; off; off >>= 1) v += __shfl_down(v, off);
  if (lane == 0) aw[n * NH + w] = v;
}

// ---------------- K3: ex = exp(leaky(aw_r+aw_c)); den += ex -----------------
__global__ __launch_bounds__(256)
void k3_den(const int* __restrict__ rows, const int* __restrict__ cols,
            const float* __restrict__ aw, float* __restrict__ den,
            float* __restrict__ exc, int E) {
  int idx = blockIdx.x * 256 + threadIdx.x;
  if (idx >= E * NH) return;
  int e = idx >> 3, h = idx & 7;
  int r = rows[e], c = cols[e];
  float s = aw[r * NH + h] + aw[c * NH + h];
  float lr = s > 0.f ? s : 0.2f * s;
  float v = __expf(lr);
  exc[idx] = v;
  atomicAdd(&den[r * NH + h], v);
}

// ---------------- K3b: coef = ex / den[row]  (in place) ---------------------
__global__ __launch_bounds__(256)
void k3b_coef(const int* __restrict__ rows, const float* __restrict__ den,
              float* __restrict__ exc, int E) {
  int idx = blockIdx.x * 256 + threadIdx.x;
  if (idx >= E * NH) return;
  int e = idx >> 3, h = idx & 7;
  exc[idx] = exc[idx] / den[rows[e] * NH + h];
}

// ---------------- K4: acc[r,f] += sum_h coef[e,h] * T[c,h*64+f] -------------
__global__ __launch_bounds__(256)
void k4_agg(const int* __restrict__ rows, const int* __restrict__ cols,
            const float* __restrict__ coef, const _Float16* __restrict__ Th,
            float* __restrict__ acc, int E) {
  int wid = (int)((blockIdx.x * (size_t)256 + threadIdx.x) >> 6);
  int lane = threadIdx.x & 63;
  if (wid >= E) return;
  int r = rows[wid], c = cols[wid];
  float4 c0 = reinterpret_cast<const float4*>(&coef[(size_t)wid * NH])[0];
  float4 c1 = reinterpret_cast<const float4*>(&coef[(size_t)wid * NH])[1];
  const _Float16* tr = Th + (size_t)c * FC + lane;
  float sum = 0.f;
  sum = fmaf(c0.x, (float)tr[0 * FO], sum);
  sum = fmaf(c0.y, (float)tr[1 * FO], sum);
  sum = fmaf(c0.z, (float)tr[2 * FO], sum);
  sum = fmaf(c0.w, (float)tr[3 * FO], sum);
  sum = fmaf(c1.x, (float)tr[4 * FO], sum);
  sum = fmaf(c1.y, (float)tr[5 * FO], sum);
  sum = fmaf(c1.z, (float)tr[6 * FO], sum);
  sum = fmaf(c1.w, (float)tr[7 * FO], sum);
  atomicAdd(&acc[(size_t)r * FO + lane], sum);
}

// ---------------- K5: out = relu((acc + sum_h b[h]) / 8) --------------------
__global__ __launch_bounds__(256)
void k5_final(const float* __restrict__ acc, const float* __restrict__ b,
              float* __restrict__ out, int N) {
  int idx = blockIdx.x * 256 + threadIdx.x;
  if (idx >= N * FO) return;
  int f = idx & (FO - 1);
  float sb = 0.f;
  #pragma unroll
  for (int h = 0; h < NH; ++h) sb += b[h * FO + f];
  float v = (acc[idx] + sb) * 0.125f;
  out[idx] = v > 0.f ? v : 0.f;
}

extern "C" void kernel_launch(void* const* d_in, const int* in_sizes, int n_in,
                              void* d_out, int out_size, void* d_ws, size_t ws_size,
                              hipStream_t stream) {
  const float* x    = (const float*)d_in[0];
  const float* W    = (const float*)d_in[1];
  const float* a    = (const float*)d_in[2];
  const float* b    = (const float*)d_in[3];
  const int*   rows = (const int*)d_in[4];
  const int*   cols = (const int*)d_in[5];
  const int N = in_sizes[0] / FI;
  const int E = in_sizes[4];

  char* p = (char*)d_ws;
  _Float16* Th  = (_Float16*)p;            p += (size_t)N * FC * sizeof(_Float16);
  _Float16* xh  = (_Float16*)p;            // aliased by acc after K1
  float*    acc = (float*)p;               p += (size_t)N * FI * sizeof(_Float16);
  _Float16* Wth = (_Float16*)p;            p += (size_t)NH * FO * FI * sizeof(_Float16);
  float*    aw  = (float*)p;               p += (size_t)N * NH * sizeof(float);
  float*    den = (float*)p;               p += (size_t)N * NH * sizeof(float);
  float*    exc = (float*)p;               p += (size_t)E * NH * sizeof(float);
  float*    out = (float*)d_out;

  hipMemsetAsync(den, 0, (size_t)N * NH * sizeof(float), stream);

  int total4 = N * FI / 4;
  p0_xconv<<<(total4 + 255) / 256, 256, 0, stream>>>(x, xh, total4);
  p1_wconv<<<(NH * FO * FI + 255) / 256, 256, 0, stream>>>(W, Wth);
  k1_mfma<<<dim3((N + 63) / 64, NH), 256, 0, stream>>>(xh, Wth, Th, N);

  // acc aliases xh; K1 (reader of xh) completes before this memset in-stream.
  hipMemsetAsync(acc, 0, (size_t)N * FO * sizeof(float), stream);

  k2_aw<<<N, 512, 0, stream>>>(Th, a, aw, N);
  k3_den<<<(E * NH + 255) / 256, 256, 0, stream>>>(rows, cols, aw, den, exc, E);
  k3b_coef<<<(E * NH + 255) / 256, 256, 0, stream>>>(rows, den, exc, E);
  k4_agg<<<(E + 3) / 4, 256, 0, stream>>>(rows, cols, exc, Th, acc, E);
  k5_final<<<(N * FO + 255) / 256, 256, 0, stream>>>(acc, b, out, N);
}